// Round 5
// baseline (225.895 us; speedup 1.0000x reference)
//
#include <hip/hip_runtime.h>
#include <hip/hip_bf16.h>
#include <stdint.h>

typedef __attribute__((ext_vector_type(8))) short bf16x8;
typedef __attribute__((ext_vector_type(4))) float f32x4;
typedef __attribute__((ext_vector_type(8))) unsigned short ushort8;

__device__ __forceinline__ unsigned short cvt1(float f) {
  union { __hip_bfloat16 b; unsigned short u; } v;
  v.b = __float2bfloat16(f);
  return v.u;
}

// ---------------- cast + transpose W: wt[n][k] = bf16(W[k][n]) ----------------
__global__ void cast_wt_kernel(const float* __restrict__ W,
                               unsigned short* __restrict__ wt) {
  int t = blockIdx.x * blockDim.x + threadIdx.x;  // 512*512 threads
  int n = t >> 9;
  int k = t & 511;
  wt[t] = cvt1(W[k * 512 + n]);
}

#define LDSTRIDE 520  // 64 rows x 520 elems bf16; 1040B row stride -> 2-way max bank alias

// ---------------- fused GEMM + bias + relu + LN-stats ----------------
// Block: 64 rows x 512 cols. Wave wid owns cols [wid*128, wid*128+128) == head wid.
// A: x fp32 read ONCE per block, cvt+staged to padded LDS (no swizzle needed).
// B: wt bf16 (0.5 MB, L2-resident) register-double-buffered straight from global.
// K-loop: 16 steps, NO barriers, NO inline asm — compiler emits counted vmcnt.
// LN per (row, head) is wave-local: shuffle reduce over the 16-lane col group.
__global__ __launch_bounds__(256, 2) void gemm_ln_kernel(
    const float* __restrict__ x,             // [N][512] fp32
    const unsigned short* __restrict__ wt,   // [512][512] bf16 (W^T)
    const float* __restrict__ bias,          // [512]
    unsigned short* __restrict__ h,          // [N][512] bf16
    float2* __restrict__ mr,                 // [N][4] (mean, rstd)
    int N) {
  __shared__ __align__(16) unsigned short As[64 * LDSTRIDE];

  const int tid = threadIdx.x;
  const int m0 = blockIdx.x << 6;

  // ---- stage A: 64 rows x 512 k, fp32 -> bf16, one shot ----
  {
    const int srow = tid & 15;        // row within 16-row batch (distinct per lane group)
    const int kb = (tid >> 4) << 5;   // k base: 0..480 step 32
#pragma unroll
    for (int b = 0; b < 4; b++) {
      const int row = (b << 4) + srow;
      const long rg = min(m0 + row, N - 1);
      const float4* src = (const float4*)(x + rg * 512 + kb);
      float4 v[8];
#pragma unroll
      for (int j = 0; j < 8; j++) v[j] = src[j];
      unsigned short* dst = As + row * LDSTRIDE + kb;
#pragma unroll
      for (int j = 0; j < 4; j++) {
        ushort8 o;
        o[0] = cvt1(v[2 * j].x);     o[1] = cvt1(v[2 * j].y);
        o[2] = cvt1(v[2 * j].z);     o[3] = cvt1(v[2 * j].w);
        o[4] = cvt1(v[2 * j + 1].x); o[5] = cvt1(v[2 * j + 1].y);
        o[6] = cvt1(v[2 * j + 1].z); o[7] = cvt1(v[2 * j + 1].w);
        *(ushort8*)(dst + (j << 3)) = o;
      }
    }
  }

  const int lane = tid & 63;
  const int wid = tid >> 6;
  const int rsel = lane & 15;
  const int k8l = lane >> 4;

  // B fragment bases: frag n covers cols wid*128 + n*16 + rsel, k-slot k8l
  const unsigned short* bB[8];
#pragma unroll
  for (int j = 0; j < 8; j++)
    bB[j] = wt + (long)((wid << 7) + (j << 4) + rsel) * 512 + (k8l << 3);

  // A fragment LDS offsets (elem units): row m*16+rsel, k-slot k8l, +t*32/step
  int aOff[4];
#pragma unroll
  for (int m = 0; m < 4; m++)
    aOff[m] = ((m << 4) + rsel) * LDSTRIDE + (k8l << 3);

  __syncthreads();  // A tile ready; the ONLY barrier before epilogue

  f32x4 acc[4][8];
#pragma unroll
  for (int m = 0; m < 4; m++)
#pragma unroll
    for (int n = 0; n < 8; n++) acc[m][n] = (f32x4){0.f, 0.f, 0.f, 0.f};

  bf16x8 bA[8], bBuf[8];
#pragma unroll
  for (int j = 0; j < 8; j++) bA[j] = *(const bf16x8*)(bB[j]);

#define KSTEP(T, CUR, NXT)                                              \
  {                                                                     \
    if ((T) < 15) {                                                     \
      _Pragma("unroll") for (int j = 0; j < 8; j++)                     \
          NXT[j] = *(const bf16x8*)(bB[j] + ((T) + 1) * 32);            \
    }                                                                   \
    bf16x8 af[4];                                                       \
    _Pragma("unroll") for (int m = 0; m < 4; m++)                       \
        af[m] = *(const bf16x8*)(As + aOff[m] + (T) * 32);              \
    _Pragma("unroll") for (int m = 0; m < 4; m++)                       \
        _Pragma("unroll") for (int n = 0; n < 8; n++)                   \
            acc[m][n] = __builtin_amdgcn_mfma_f32_16x16x32_bf16(        \
                af[m], CUR[n], acc[m][n], 0, 0, 0);                     \
  }

#pragma unroll
  for (int tt = 0; tt < 8; tt++) {
    KSTEP(tt * 2, bA, bBuf);
    KSTEP(tt * 2 + 1, bBuf, bA);
  }
#undef KSTEP

  // ---- epilogue: bias + relu, h bf16 store, wave-local LN stats ----
  const int colb = (wid << 7) + rsel;
  float bval[8];
#pragma unroll
  for (int n = 0; n < 8; n++) bval[n] = bias[colb + (n << 4)];

#pragma unroll
  for (int m = 0; m < 4; m++) {
#pragma unroll
    for (int i = 0; i < 4; i++) {
      const int row_l = (m << 4) + (k8l << 2) + i;
      const long row_g = m0 + row_l;
      const bool valid = row_g < N;
      float s = 0.f, q = 0.f;
#pragma unroll
      for (int n = 0; n < 8; n++) {
        float v = acc[m][n][i] + bval[n];
        v = fmaxf(v, 0.f);
        s += v;
        q += v * v;
        if (valid) h[row_g * 512 + colb + (n << 4)] = cvt1(v);
      }
#pragma unroll
      for (int d = 1; d < 16; d <<= 1) {
        s += __shfl_xor(s, d, 64);
        q += __shfl_xor(q, d, 64);
      }
      if (valid && rsel == 0) {
        float mean = s * (1.f / 128.f);
        float var = q * (1.f / 128.f) - mean * mean;
        mr[row_g * 4 + wid] = make_float2(mean, rsqrtf(var + 1e-5f));
      }
    }
  }
}

// ---------------- per-graph online segment softmax + weighted pooling ----------------
__global__ __launch_bounds__(512) void pool_kernel(
    const unsigned short* __restrict__ h, const float2* __restrict__ mr,
    const float* __restrict__ qs, const int* __restrict__ gidx,
    float* __restrict__ out, int N) {
  const int g = blockIdx.x;
  const int ch = threadIdx.x;

  int lo = 0, hi = N;
  while (lo < hi) {
    int mid = (lo + hi) >> 1;
    if (gidx[mid] < g) lo = mid + 1; else hi = mid;
  }
  const int s0 = lo;
  hi = N;
  while (lo < hi) {
    int mid = (lo + hi) >> 1;
    if (gidx[mid] < g + 1) lo = mid + 1; else hi = mid;
  }
  const int e0 = lo;

  const float qscale = qs[ch];
  const int head = ch >> 7;
  float m = -INFINITY, S = 0.f, Nm = 0.f;

  int n = s0;
  for (; n + 4 <= e0; n += 4) {
    float hv[4];
    float2 mv[4];
#pragma unroll
    for (int j = 0; j < 4; j++) {
      hv[j] = __uint_as_float((unsigned int)h[(long)(n + j) * 512 + ch] << 16);
      mv[j] = mr[(long)(n + j) * 4 + head];
    }
#pragma unroll
    for (int j = 0; j < 4; j++) {
      float qv = (hv[j] - mv[j].x) * mv[j].y * qscale;
      float nm = fmaxf(m, qv);
      float c = __expf(m - nm);
      float p = __expf(qv - nm);
      S = S * c + p;
      Nm = Nm * c + p * hv[j];
      m = nm;
    }
  }
  for (; n < e0; ++n) {
    float hv = __uint_as_float((unsigned int)h[(long)n * 512 + ch] << 16);
    float2 mv = mr[(long)n * 4 + head];
    float qv = (hv - mv.x) * mv.y * qscale;
    float nm = fmaxf(m, qv);
    float c = __expf(m - nm);
    float p = __expf(qv - nm);
    S = S * c + p;
    Nm = Nm * c + p * hv;
    m = nm;
  }
  out[g * 512 + ch] = Nm / (S + 1e-16f);
}

extern "C" void kernel_launch(void* const* d_in, const int* in_sizes, int n_in,
                              void* d_out, int out_size, void* d_ws, size_t ws_size,
                              hipStream_t stream) {
  const float* x = (const float*)d_in[0];
  const float* W = (const float*)d_in[1];
  const float* bias = (const float*)d_in[2];
  const float* qs = (const float*)d_in[3];
  const int* gidx = (const int*)d_in[4];
  const int N = in_sizes[0] / 512;
  const int B = out_size / 512;
  float* out = (float*)d_out;

  char* ws = (char*)d_ws;
  size_t off = 0;
  auto alloc = [&](size_t bytes) {
    char* p = ws + off;
    off += (bytes + 255) & ~(size_t)255;
    return p;
  };
  unsigned short* wt = (unsigned short*)alloc((size_t)512 * 512 * 2);
  unsigned short* h = (unsigned short*)alloc((size_t)N * 512 * 2);
  float2* mr = (float2*)alloc((size_t)N * 4 * sizeof(float2));
  (void)ws_size;  // need ~104 MB

  cast_wt_kernel<<<(512 * 512) / 256, 256, 0, stream>>>(W, wt);
  const int mblocks = (N + 63) / 64;
  gemm_ln_kernel<<<mblocks, 256, 0, stream>>>(x, wt, bias, h, mr, N);
  pool_kernel<<<B, 512, 0, stream>>>(h, mr, qs, gidx, out, N);
}

// Round 6
// 167.049 us; speedup vs baseline: 1.3523x; 1.3523x over previous
//
#include <hip/hip_runtime.h>
#include <hip/hip_bf16.h>
#include <stdint.h>

typedef __attribute__((ext_vector_type(8))) short bf16x8;
typedef __attribute__((ext_vector_type(4))) float f32x4;
typedef __attribute__((ext_vector_type(8))) unsigned short ushort8;

__device__ __forceinline__ unsigned short cvt1(float f) {
  union { __hip_bfloat16 b; unsigned short u; } v;
  v.b = __float2bfloat16(f);
  return v.u;
}

__device__ __forceinline__ void gld_lds16(const void* g, void* l) {
  __builtin_amdgcn_global_load_lds(
      (const __attribute__((address_space(1))) unsigned int*)g,
      (__attribute__((address_space(3))) unsigned int*)l,
      16, 0, 0);
}

// ---------------- cast + transpose W: wt[n][k] = bf16(W[k][n]) ----------------
__global__ void cast_wt_kernel(const float* __restrict__ W,
                               unsigned short* __restrict__ wt) {
  int t = blockIdx.x * blockDim.x + threadIdx.x;  // 512*512 threads
  int n = t >> 9;
  int k = t & 511;
  wt[t] = cvt1(W[k * 512 + n]);
}

// ---------------- fused GEMM + bias + relu + LN-stats ----------------
// r2/m97 skeleton: gld_lds staging for BOTH operands, 2 syncthreads/K-step,
// no inline asm, high block residency (LDS 49KB -> 3 blocks/CU).
// Tile 128x128, BK=64, 4 waves (2x2), mfma_f32_16x16x32_bf16, 4x4 frags/wave.
// A: x staged as FP32 via gld_lds (32KB), cvt->bf16 at fragment read.
//    LDS layout: row stride 256B, 16 slots of 16B, slot = k4 ^ (row&15).
// B: wt bf16 via gld_lds (16KB), row stride 128B, slot = k8 ^ (row&7).
// h out bf16; LN mean/rstd per (row, head=ntile) as float2.
__global__ __launch_bounds__(256, 3) void gemm_ln_kernel(
    const float* __restrict__ x,             // [N][512] fp32
    const unsigned short* __restrict__ wt,   // [512][512] bf16 (W^T)
    const float* __restrict__ bias,          // [512]
    unsigned short* __restrict__ h,          // [N][512] bf16
    float2* __restrict__ mr,                 // [N][4] (mean, rstd)
    int N, int mtiles) {
  __shared__ __align__(16) char AsRaw[128 * 64 * 4];   // fp32 A tile, 32KB
  __shared__ __align__(16) char BsRaw[128 * 64 * 2];   // bf16 B tile, 16KB
  __shared__ float redS[128 * 2];
  __shared__ float redQ[128 * 2];

  // ---- XCD-grouped bid remap: 4 ntile-peers of an mtile share bid%8 ----
  const int nfull = (mtiles >> 3) << 3;
  const int full_bids = nfull * 4;
  int mtile, ntile;
  {
    const int bid = blockIdx.x;
    if (bid < full_bids) {
      const int chunk = bid >> 5, j = bid & 31;
      mtile = (chunk << 3) + (j & 7);
      ntile = j >> 3;
    } else {
      const int j = bid - full_bids;
      const int rem = mtiles - nfull;
      mtile = nfull + j % rem;
      ntile = j / rem;
    }
  }
  const int m0 = mtile << 7;
  const int n0 = ntile << 7;

  const int tid = threadIdx.x;
  const int lane = tid & 63;
  const int wid = tid >> 6;
  const int wr = wid >> 1;
  const int wc = wid & 1;

  f32x4 acc[4][4];
#pragma unroll
  for (int m = 0; m < 4; m++)
#pragma unroll
    for (int n = 0; n < 4; n++) acc[m][n] = (f32x4){0.f, 0.f, 0.f, 0.f};

  // ---- A staging geometry: 8 x 4KB regions, pre-swizzled global source ----
  const float* aP[8];
  int aLds[8];
#pragma unroll
  for (int L = 0; L < 8; L++) {
    const int p = (L << 12) + tid * 16;  // byte pos in 32KB tile
    const int row = p >> 8;              // 256B per row
    const int slot = (p >> 4) & 15;
    const int k4 = slot ^ (row & 15);
    aP[L] = x + (long)min(m0 + row, N - 1) * 512 + k4 * 4;
    aLds[L] = (L << 12) + (wid << 10);   // wave-uniform chunk base
  }

  // ---- B staging geometry: 4 x 4KB regions, pre-swizzled global source ----
  const unsigned short* bP[4];
  int bLds[4];
#pragma unroll
  for (int L = 0; L < 4; L++) {
    const int p = (L << 12) + tid * 16;  // byte pos in 16KB tile
    const int row = p >> 7;              // 128B per row
    const int slot = (p >> 4) & 7;
    const int k8 = slot ^ (row & 7);
    bP[L] = wt + (long)(n0 + row) * 512 + k8 * 8;
    bLds[L] = (L << 12) + (wid << 10);
  }

  // ---- fragment read offsets (kk=0 base; derive kk/h by XOR) ----
  const int rsel = lane & 15;
  const int k8l = lane >> 4;
  int offA[4], offB[4];
#pragma unroll
  for (int m = 0; m < 4; m++) {
    const int ra = wr * 64 + m * 16 + rsel;
    offA[m] = ra * 256 + (((k8l << 1) ^ (ra & 15)) << 4);  // h -> ^16, kk -> ^128
    const int rb = wc * 64 + m * 16 + rsel;
    offB[m] = rb * 128 + ((k8l ^ (rb & 7)) << 4);          // kk -> ^64
  }

#pragma unroll
  for (int t = 0; t < 8; t++) {
    // stage tile t (compiler emits waits; barrier drains)
#pragma unroll
    for (int L = 0; L < 8; L++) gld_lds16(aP[L] + (t << 6), AsRaw + aLds[L]);
#pragma unroll
    for (int L = 0; L < 4; L++) gld_lds16(bP[L] + (t << 6), BsRaw + bLds[L]);
    __syncthreads();

#pragma unroll
    for (int kk = 0; kk < 2; kk++) {
      bf16x8 af[4], bq[4];
#pragma unroll
      for (int m = 0; m < 4; m++) {
        const int o = offA[m] ^ (kk << 7);
        const f32x4 r0 = *(const f32x4*)(AsRaw + o);
        const f32x4 r1 = *(const f32x4*)(AsRaw + (o ^ 16));
        ushort8 u;
        u[0] = cvt1(r0[0]); u[1] = cvt1(r0[1]);
        u[2] = cvt1(r0[2]); u[3] = cvt1(r0[3]);
        u[4] = cvt1(r1[0]); u[5] = cvt1(r1[1]);
        u[6] = cvt1(r1[2]); u[7] = cvt1(r1[3]);
        af[m] = (bf16x8)u;
      }
#pragma unroll
      for (int n = 0; n < 4; n++)
        bq[n] = *(const bf16x8*)(BsRaw + (offB[n] ^ (kk << 6)));
#pragma unroll
      for (int m = 0; m < 4; m++)
#pragma unroll
        for (int n = 0; n < 4; n++)
          acc[m][n] = __builtin_amdgcn_mfma_f32_16x16x32_bf16(
              af[m], bq[n], acc[m][n], 0, 0, 0);
    }
    __syncthreads();
  }

  // ---- epilogue: bias + relu, store h bf16, per-row sum/sumsq ----
  const int colb = n0 + wc * 64 + rsel;
  float bval[4];
#pragma unroll
  for (int n = 0; n < 4; n++) bval[n] = bias[colb + n * 16];

#pragma unroll
  for (int m = 0; m < 4; m++) {
    const int rbase = wr * 64 + m * 16 + (k8l << 2);
#pragma unroll
    for (int i = 0; i < 4; i++) {
      const int row_l = rbase + i;
      const long row_g = (long)m0 + row_l;
      const bool valid = row_g < N;
      float s = 0.f, q = 0.f;
#pragma unroll
      for (int n = 0; n < 4; n++) {
        float v = acc[m][n][i] + bval[n];
        v = fmaxf(v, 0.f);
        s += v;
        q += v * v;
        if (valid) h[row_g * 512 + colb + n * 16] = cvt1(v);
      }
#pragma unroll
      for (int d = 1; d < 16; d <<= 1) {
        s += __shfl_xor(s, d, 64);
        q += __shfl_xor(q, d, 64);
      }
      if (rsel == 0) {
        redS[row_l * 2 + wc] = s;
        redQ[row_l * 2 + wc] = q;
      }
    }
  }
  __syncthreads();
  if (tid < 128) {
    const long row_g = (long)m0 + tid;
    if (row_g < N) {
      float s = redS[tid * 2] + redS[tid * 2 + 1];
      float q = redQ[tid * 2] + redQ[tid * 2 + 1];
      float mean = s * (1.f / 128.f);
      float var = q * (1.f / 128.f) - mean * mean;
      mr[row_g * 4 + ntile] = make_float2(mean, rsqrtf(var + 1e-5f));
    }
  }
}

// ---------------- per-graph online segment softmax + weighted pooling ----------------
// 512 threads = 4 row-slots x 128 channel-quads. Each thread keeps 4 online
// softmax chains (its 4 channels) over rows s0+rs, s0+rs+4, ...; LDS merge.
__global__ __launch_bounds__(512) void pool_kernel(
    const unsigned short* __restrict__ h, const float2* __restrict__ mr,
    const float* __restrict__ qs, const int* __restrict__ gidx,
    float* __restrict__ out, int N) {
  __shared__ float sm[4][512], ss[4][512], sp[4][512];

  const int g = blockIdx.x;
  const int tid = threadIdx.x;
  const int rs = tid >> 7;
  const int c4 = tid & 127;
  const int ch0 = c4 << 2;
  const int head = c4 >> 5;

  int lo = 0, hi = N;
  while (lo < hi) {
    int mid = (lo + hi) >> 1;
    if (gidx[mid] < g) lo = mid + 1; else hi = mid;
  }
  const int s0 = lo;
  hi = N;
  while (lo < hi) {
    int mid = (lo + hi) >> 1;
    if (gidx[mid] < g + 1) lo = mid + 1; else hi = mid;
  }
  const int e0 = lo;

  const float4 q4 = *(const float4*)(qs + ch0);
  float m_[4], S_[4], P_[4];
#pragma unroll
  for (int j = 0; j < 4; j++) { m_[j] = -INFINITY; S_[j] = 0.f; P_[j] = 0.f; }

  for (int n = s0 + rs; n < e0; n += 4) {
    const ushort4 hu = *(const ushort4*)(h + (long)n * 512 + ch0);
    const float2 mv = mr[(long)n * 4 + head];
    const float hs[4] = {
        __uint_as_float((unsigned int)hu.x << 16),
        __uint_as_float((unsigned int)hu.y << 16),
        __uint_as_float((unsigned int)hu.z << 16),
        __uint_as_float((unsigned int)hu.w << 16)};
    const float qf[4] = {q4.x, q4.y, q4.z, q4.w};
#pragma unroll
    for (int j = 0; j < 4; j++) {
      const float qv = (hs[j] - mv.x) * mv.y * qf[j];
      const float nm = fmaxf(m_[j], qv);
      const float c = __expf(m_[j] - nm);
      const float p = __expf(qv - nm);
      S_[j] = S_[j] * c + p;
      P_[j] = P_[j] * c + p * hs[j];
      m_[j] = nm;
    }
  }

#pragma unroll
  for (int j = 0; j < 4; j++) {
    sm[rs][ch0 + j] = m_[j];
    ss[rs][ch0 + j] = S_[j];
    sp[rs][ch0 + j] = P_[j];
  }
  __syncthreads();

  if (rs == 0) {
    float4 res;
#pragma unroll
    for (int j = 0; j < 4; j++) {
      const int ch = ch0 + j;
      float M = sm[0][ch];
#pragma unroll
      for (int r = 1; r < 4; r++) M = fmaxf(M, sm[r][ch]);
      float S = 0.f, P = 0.f;
#pragma unroll
      for (int r = 0; r < 4; r++) {
        if (sm[r][ch] != -INFINITY) {
          const float f = __expf(sm[r][ch] - M);
          S += ss[r][ch] * f;
          P += sp[r][ch] * f;
        }
      }
      ((float*)&res)[j] = P / (S + 1e-16f);
    }
    *(float4*)(out + (long)g * 512 + ch0) = res;
  }
}

extern "C" void kernel_launch(void* const* d_in, const int* in_sizes, int n_in,
                              void* d_out, int out_size, void* d_ws, size_t ws_size,
                              hipStream_t stream) {
  const float* x = (const float*)d_in[0];
  const float* W = (const float*)d_in[1];
  const float* bias = (const float*)d_in[2];
  const float* qs = (const float*)d_in[3];
  const int* gidx = (const int*)d_in[4];
  const int N = in_sizes[0] / 512;
  const int B = out_size / 512;
  float* out = (float*)d_out;

  char* ws = (char*)d_ws;
  size_t off = 0;
  auto alloc = [&](size_t bytes) {
    char* p = ws + off;
    off += (bytes + 255) & ~(size_t)255;
    return p;
  };
  unsigned short* wt = (unsigned short*)alloc((size_t)512 * 512 * 2);
  unsigned short* h = (unsigned short*)alloc((size_t)N * 512 * 2);
  float2* mr = (float2*)alloc((size_t)N * 4 * sizeof(float2));
  (void)ws_size;  // need ~107 MB

  cast_wt_kernel<<<(512 * 512) / 256, 256, 0, stream>>>(W, wt);
  const int mtiles = (N + 127) / 128;
  gemm_ln_kernel<<<mtiles * 4, 256, 0, stream>>>(x, wt, bias, h, mr, N, mtiles);
  pool_kernel<<<B, 512, 0, stream>>>(h, mr, qs, gidx, out, N);
}